// Round 7
// baseline (143.158 us; speedup 1.0000x reference)
//
#include <hip/hip_runtime.h>
#include <hip/hip_cooperative_groups.h>

// B = 262144 rows, 256 -> 64 (relu) -> 16 (tanh) -> 4 -> global softmax.
// Layer 1 & 2 on MFMA f16 with 2-way split operands (3-term products),
// power-of-2 scaled so split residuals stay f16-normal.
// R7: R5 pipeline + double-buffered xv prefetch (HBM queue never empties)
//     + cooperative grid.sync to fold the softmax scale into one kernel.

namespace cg = cooperative_groups;

typedef _Float16 half8 __attribute__((ext_vector_type(8)));
typedef _Float16 half4 __attribute__((ext_vector_type(4)));
typedef float f32x4 __attribute__((ext_vector_type(4)));

#define GRID 256
#define TPB  512
#define TROWS 64

#define XS  264   // f16 stride for x rows (256 + 8 pad)
#define WS  264   // w1T stride
#define H1S 72    // h1 [row][j] stride (64 + 8)
#define W2S 72    // w2T stride

#define SCALE_IN 256.0f            // 2^8
#define SCALE_W  2048.0f           // 2^11
#define INV_SC   (1.0f/524288.0f)  // 2^-19

// ---- LDS byte offsets (R3/R5 layout) ----
#define OFF_XH  0
#define OFF_XL  (OFF_XH + TROWS*XS*2)      // 33792
#define OFF_W1H (OFF_XL + TROWS*XS*2)      // 67584
#define OFF_W1L (OFF_W1H + 64*WS*2)        // 101376
#define OFF_H1H (OFF_W1L + 64*WS*2)        // 135168
#define OFF_H1L (OFF_H1H + TROWS*H1S*2)    // 144384
#define OFF_W2H (OFF_H1L + TROWS*H1S*2)    // 153600
#define OFF_W2L (OFF_W2H + 16*W2S*2)       // 155904
#define OFF_SUM (OFF_W2L + 16*W2S*2)       // 158208
#define SMEM_BYTES (OFF_SUM + 64*4)        // 158464 <= 163840 -> 1 block/CU

extern __shared__ char smem_raw[];

#define MFMA16(a,b,c) __builtin_amdgcn_mfma_f32_16x16x32_f16((a),(b),(c),0,0,0)

__device__ __forceinline__ void lds_barrier() {
    asm volatile("s_waitcnt lgkmcnt(0)\ns_barrier" ::: "memory");
}

__global__ __launch_bounds__(TPB, 2) void fused_mlp(
    const float* __restrict__ x,
    const float* __restrict__ wz1, const float* __restrict__ b1,
    const float* __restrict__ wz2, const float* __restrict__ b2,
    const float* __restrict__ wz3, const float* __restrict__ b3,
    float* __restrict__ Eout, float* __restrict__ block_sums,
    int ntiles)
{
    _Float16* xh  = (_Float16*)(smem_raw + OFF_XH);
    _Float16* xl  = (_Float16*)(smem_raw + OFF_XL);
    _Float16* w1h = (_Float16*)(smem_raw + OFF_W1H);
    _Float16* w1l = (_Float16*)(smem_raw + OFF_W1L);
    _Float16* h1h = (_Float16*)(smem_raw + OFF_H1H);
    _Float16* h1l = (_Float16*)(smem_raw + OFF_H1L);
    _Float16* w2h = (_Float16*)(smem_raw + OFF_W2H);
    _Float16* w2l = (_Float16*)(smem_raw + OFF_W2L);
    float* sums   = (float*)(smem_raw + OFF_SUM);

    const int tid  = threadIdx.x;
    const int lane = tid & 63;
    const int wid  = __builtin_amdgcn_readfirstlane(tid >> 6);
    const int l15  = lane & 15;
    const int g8   = (lane >> 4) * 8;

    const size_t blk_row0 = (size_t)blockIdx.x * ntiles * TROWS;

    // ---- prologue: issue x tile-0 loads first (HBM latency overlap) ----
    float4 xva[8], xvb[8];
    {
        const float4* xg = (const float4*)(x + blk_row0 * 256);
        #pragma unroll
        for (int c = 0; c < 8; ++c) xva[c] = xg[c * TPB + tid];
    }

    // ---- stage w1T as scaled f16 hi/lo (once) ----
    {
        const float4* wg = (const float4*)wz1;   // 4096 float4
        #pragma unroll
        for (int c = 0; c < 8; ++c) {
            const int q = c * TPB + tid;         // 0..4095
            const float4 v = wg[q];
            const int k = q >> 4, n0 = (q & 15) * 4;
            const float vv[4] = {v.x, v.y, v.z, v.w};
            #pragma unroll
            for (int i = 0; i < 4; ++i) {
                const float s = vv[i] * SCALE_W;
                const _Float16 h = (_Float16)s;
                w1h[(n0 + i) * WS + k] = h;
                w1l[(n0 + i) * WS + k] = (_Float16)(s - (float)h);
            }
        }
        if (tid < 256) {                         // w2T: 256 float4
            const float4 v = ((const float4*)wz2)[tid];
            const int k = tid >> 2, c0 = (tid & 3) * 4;
            const float vv[4] = {v.x, v.y, v.z, v.w};
            #pragma unroll
            for (int i = 0; i < 4; ++i) {
                const float s = vv[i] * SCALE_W;
                const _Float16 h = (_Float16)s;
                w2h[(c0 + i) * W2S + k] = h;
                w2l[(c0 + i) * W2S + k] = (_Float16)(s - (float)h);
            }
        }
    }

    // ---- per-lane constants ----
    const int rt  = wid >> 1;                 // rowtile 0..3 (layer 1)
    const int ntp = wid & 1;                  // col-pair 0..1
    const int col0 = (2 * ntp) * 16 + l15;
    const int col1 = (2 * ntp + 1) * 16 + l15;
    const float b1v0 = b1[col0], b1v1 = b1[col1];
    float b2v[4], w3v[4][4];
    #pragma unroll
    for (int i = 0; i < 4; ++i) {
        const int c2 = (lane >> 4) * 4 + i;
        b2v[i] = b2[c2];
        #pragma unroll
        for (int c3 = 0; c3 < 4; ++c3) w3v[i][c3] = wz3[c2 * 4 + c3];
    }
    const float b3v[4] = {b3[0], b3[1], b3[2], b3[3]};

    lds_barrier();   // weights staged

    // ---- persistent register fragments: w1 hi (lo stays in LDS) ----
    half8 Bh[8][2];
    #pragma unroll
    for (int kt = 0; kt < 8; ++kt) {
        Bh[kt][0] = *(const half8*)(w1h + col0 * WS + kt * 32 + g8);
        Bh[kt][1] = *(const half8*)(w1h + col1 * WS + kt * 32 + g8);
    }
    half8 A2h[2], A2l[2];                     // w2T A-frags (layer 2)
    #pragma unroll
    for (int kt = 0; kt < 2; ++kt) {
        A2h[kt] = *(const half8*)(w2h + l15 * W2S + kt * 32 + g8);
        A2l[kt] = *(const half8*)(w2l + l15 * W2S + kt * 32 + g8);
    }

    float local_sum = 0.f;

    // one tile iteration; cur = this tile's regs, nxt = buffer to prefetch into
    auto body = [&](float4 (&cur)[8], float4 (&nxt)[8], int t) {
        // ---- issue next-tile loads FIRST (keeps HBM queue non-empty) ----
        if (t + 1 < ntiles) {
            const float4* xg2 =
                (const float4*)(x + (blk_row0 + (size_t)(t + 1) * TROWS) * 256);
            #pragma unroll
            for (int c = 0; c < 8; ++c) nxt[c] = xg2[c * TPB + tid];
        }
        // ---- convert regs -> LDS f16 hi/lo (row = c*8+wid, k = lane*4) ----
        #pragma unroll
        for (int c = 0; c < 8; ++c) {
            const float vv[4] = {cur[c].x, cur[c].y, cur[c].z, cur[c].w};
            half4 hh, hl;
            #pragma unroll
            for (int i = 0; i < 4; ++i) {
                const float s = vv[i] * SCALE_IN;
                const _Float16 h = (_Float16)s;
                hh[i] = h;
                hl[i] = (_Float16)(s - (float)h);
            }
            const int row = c * 8 + wid;
            *(half4*)(xh + row * XS + lane * 4) = hh;
            *(half4*)(xl + row * XS + lane * 4) = hl;
        }
        lds_barrier();   // B1: x(t) visible

        // ---- layer 1: 3-term split MFMA; A from LDS, Bh regs, Bl LDS ----
        f32x4 acc0 = {0.f, 0.f, 0.f, 0.f}, acc1 = {0.f, 0.f, 0.f, 0.f};
        {
            const _Float16* xh_p = xh + (rt * 16 + l15) * XS;
            const _Float16* xl_p = xl + (rt * 16 + l15) * XS;
            const _Float16* wl_p0 = w1l + col0 * WS;
            const _Float16* wl_p1 = w1l + col1 * WS;
            #pragma unroll
            for (int kt = 0; kt < 8; ++kt) {
                const int ko = kt * 32 + g8;
                const half8 ah  = *(const half8*)(xh_p + ko);
                const half8 al  = *(const half8*)(xl_p + ko);
                const half8 bl0 = *(const half8*)(wl_p0 + ko);
                const half8 bl1 = *(const half8*)(wl_p1 + ko);
                acc0 = MFMA16(ah, Bh[kt][0], acc0);
                acc1 = MFMA16(ah, Bh[kt][1], acc1);
                acc0 = MFMA16(al, Bh[kt][0], acc0);
                acc1 = MFMA16(al, Bh[kt][1], acc1);
                acc0 = MFMA16(ah, bl0, acc0);
                acc1 = MFMA16(ah, bl1, acc1);
            }
        }
        // ---- epilogue: scale+bias+relu -> h1 f16 hi/lo ----
        #pragma unroll
        for (int i = 0; i < 4; ++i) {
            const int r = rt * 16 + (lane >> 4) * 4 + i;
            const float h0 = fmaxf(fmaf(acc0[i], INV_SC, b1v0), 0.f);
            const float h1f = fmaxf(fmaf(acc1[i], INV_SC, b1v1), 0.f);
            const float s0 = h0 * SCALE_IN;
            const _Float16 h0h = (_Float16)s0;
            h1h[r * H1S + col0] = h0h;
            h1l[r * H1S + col0] = (_Float16)(s0 - (float)h0h);
            const float s1 = h1f * SCALE_IN;
            const _Float16 h1hh = (_Float16)s1;
            h1h[r * H1S + col1] = h1hh;
            h1l[r * H1S + col1] = (_Float16)(s1 - (float)h1hh);
        }
        lds_barrier();   // B2: h1 ready

        // ---- layer 2 (MFMA) + layer 3 + exp: waves 0..3 ----
        if (wid < 4) {
            f32x4 a2 = {0.f, 0.f, 0.f, 0.f};
            const _Float16* hh_p = h1h + (wid * 16 + l15) * H1S;
            const _Float16* hl_p = h1l + (wid * 16 + l15) * H1S;
            #pragma unroll
            for (int kt = 0; kt < 2; ++kt) {
                const int ko = kt * 32 + g8;
                const half8 bh = *(const half8*)(hh_p + ko);
                const half8 bl = *(const half8*)(hl_p + ko);
                a2 = MFMA16(A2h[kt], bh, a2);
                a2 = MFMA16(A2l[kt], bh, a2);
                a2 = MFMA16(A2h[kt], bl, a2);
            }
            float p0 = 0.f, p1 = 0.f, p2 = 0.f, p3 = 0.f;
            #pragma unroll
            for (int i = 0; i < 4; ++i) {
                const float h2 = tanhf(fmaf(a2[i], INV_SC, b2v[i]));
                p0 = fmaf(h2, w3v[i][0], p0);
                p1 = fmaf(h2, w3v[i][1], p1);
                p2 = fmaf(h2, w3v[i][2], p2);
                p3 = fmaf(h2, w3v[i][3], p3);
            }
            p0 += __shfl_xor(p0, 16, 64); p0 += __shfl_xor(p0, 32, 64);
            p1 += __shfl_xor(p1, 16, 64); p1 += __shfl_xor(p1, 32, 64);
            p2 += __shfl_xor(p2, 16, 64); p2 += __shfl_xor(p2, 32, 64);
            p3 += __shfl_xor(p3, 16, 64); p3 += __shfl_xor(p3, 32, 64);
            if (lane < 16) {
                const float e0 = expf(p0 + b3v[0]);
                const float e1 = expf(p1 + b3v[1]);
                const float e2 = expf(p2 + b3v[2]);
                const float e3 = expf(p3 + b3v[3]);
                const size_t row = blk_row0 + (size_t)t * TROWS + wid * 16 + lane;
                float4 ev; ev.x = e0; ev.y = e1; ev.z = e2; ev.w = e3;
                *(float4*)(Eout + row * 4) = ev;
                local_sum += (e0 + e1) + (e2 + e3);
            }
        }
    };

    for (int tp = 0; tp < ntiles; tp += 2) {   // ntiles even; static buffers
        body(xva, xvb, tp);
        body(xvb, xva, tp + 1);
    }

    // ---- block exp-sum reduction (deterministic) ----
    #pragma unroll
    for (int off = 32; off > 0; off >>= 1)
        local_sum += __shfl_down(local_sum, off, 64);
    if (lane == 0) sums[wid] = local_sum;
    lds_barrier();
    if (tid == 0) {
        float s = 0.f;
        #pragma unroll
        for (int w = 0; w < 8; ++w) s += sums[w];
        block_sums[blockIdx.x] = s;
    }
    __threadfence();

    // ---- grid-wide sync, then in-kernel softmax scale ----
    cg::this_grid().sync();

    {
        float s = 0.f;
        if (wid < 4) s = block_sums[(wid << 6) | lane];
        #pragma unroll
        for (int off = 32; off > 0; off >>= 1) s += __shfl_down(s, off, 64);
        if (wid < 4 && lane == 0) sums[wid] = s;
        lds_barrier();
        const float inv = 1.0f / ((sums[0] + sums[1]) + (sums[2] + sums[3]));

        // scale own E chunk: 1024 float4 per block (L2-hot, own XCD)
        float4* o4 = (float4*)Eout;
        const size_t base = blk_row0;   // 1 float4 per row
        #pragma unroll
        for (int i = 0; i < 2; ++i) {
            const size_t idx = base + (size_t)i * TPB + tid;
            float4 v = o4[idx];
            v.x *= inv; v.y *= inv; v.z *= inv; v.w *= inv;
            o4[idx] = v;
        }
    }
}

extern "C" void kernel_launch(void* const* d_in, const int* in_sizes, int n_in,
                              void* d_out, int out_size, void* d_ws, size_t ws_size,
                              hipStream_t stream) {
    (void)n_in; (void)ws_size; (void)out_size;
    const float* x   = (const float*)d_in[0];
    const float* wz1 = (const float*)d_in[1];
    const float* b1  = (const float*)d_in[2];
    const float* wz2 = (const float*)d_in[3];
    const float* b2  = (const float*)d_in[4];
    const float* wz3 = (const float*)d_in[5];
    const float* b3  = (const float*)d_in[6];
    float* out = (float*)d_out;

    float* block_sums = (float*)d_ws;            // GRID floats

    const int B = in_sizes[0] / 256;             // 262144
    int ntiles = B / (GRID * TROWS);             // 16

    hipFuncSetAttribute((const void*)fused_mlp,
                        hipFuncAttributeMaxDynamicSharedMemorySize, SMEM_BYTES);

    void* args[] = {(void*)&x, (void*)&wz1, (void*)&b1, (void*)&wz2,
                    (void*)&b2, (void*)&wz3, (void*)&b3,
                    (void*)&out, (void*)&block_sums, (void*)&ntiles};
    hipLaunchCooperativeKernel((const void*)fused_mlp, dim3(GRID), dim3(TPB),
                               args, SMEM_BYTES, stream);
}

// Round 8
// 135.768 us; speedup vs baseline: 1.0544x; 1.0544x over previous
//
#include <hip/hip_runtime.h>
#include <hip/hip_cooperative_groups.h>

// B = 262144 rows, 256 -> 64 (relu) -> 16 (tanh) -> 4 -> global softmax.
// Layer 1 & 2 on MFMA f16 with 2-way split operands (3-term products),
// power-of-2 scaled so split residuals stay f16-normal.
// R8: exact R5 kernel body (regs verified no-spill at 57.4us total) +
//     cooperative grid.sync + in-kernel softmax scale (validated in R7).

namespace cg = cooperative_groups;

typedef _Float16 half8 __attribute__((ext_vector_type(8)));
typedef _Float16 half4 __attribute__((ext_vector_type(4)));
typedef float f32x4 __attribute__((ext_vector_type(4)));

#define GRID 256
#define TPB  512
#define TROWS 64

#define XS  264   // f16 stride for x rows (256 + 8 pad)
#define WS  264   // w1T stride
#define H1S 72    // h1 [row][j] stride (64 + 8)
#define W2S 72    // w2T stride

#define SCALE_IN 256.0f            // 2^8
#define SCALE_W  2048.0f           // 2^11
#define INV_SC   (1.0f/524288.0f)  // 2^-19

// ---- LDS byte offsets (R3/R5 layout) ----
#define OFF_XH  0
#define OFF_XL  (OFF_XH + TROWS*XS*2)      // 33792
#define OFF_W1H (OFF_XL + TROWS*XS*2)      // 67584
#define OFF_W1L (OFF_W1H + 64*WS*2)        // 101376
#define OFF_H1H (OFF_W1L + 64*WS*2)        // 135168
#define OFF_H1L (OFF_H1H + TROWS*H1S*2)    // 144384
#define OFF_W2H (OFF_H1L + TROWS*H1S*2)    // 153600
#define OFF_W2L (OFF_W2H + 16*W2S*2)       // 155904
#define OFF_SUM (OFF_W2L + 16*W2S*2)       // 158208
#define SMEM_BYTES (OFF_SUM + 64*4)        // 158464 <= 163840 -> 1 block/CU

extern __shared__ char smem_raw[];

#define MFMA16(a,b,c) __builtin_amdgcn_mfma_f32_16x16x32_f16((a),(b),(c),0,0,0)

__device__ __forceinline__ void lds_barrier() {
    asm volatile("s_waitcnt lgkmcnt(0)\ns_barrier" ::: "memory");
}

__global__ __launch_bounds__(TPB, 2) void fused_mlp(
    const float* __restrict__ x,
    const float* __restrict__ wz1, const float* __restrict__ b1,
    const float* __restrict__ wz2, const float* __restrict__ b2,
    const float* __restrict__ wz3, const float* __restrict__ b3,
    float* __restrict__ Eout, float* __restrict__ block_sums,
    int ntiles)
{
    _Float16* xh  = (_Float16*)(smem_raw + OFF_XH);
    _Float16* xl  = (_Float16*)(smem_raw + OFF_XL);
    _Float16* w1h = (_Float16*)(smem_raw + OFF_W1H);
    _Float16* w1l = (_Float16*)(smem_raw + OFF_W1L);
    _Float16* h1h = (_Float16*)(smem_raw + OFF_H1H);
    _Float16* h1l = (_Float16*)(smem_raw + OFF_H1L);
    _Float16* w2h = (_Float16*)(smem_raw + OFF_W2H);
    _Float16* w2l = (_Float16*)(smem_raw + OFF_W2L);
    float* sums   = (float*)(smem_raw + OFF_SUM);

    const int tid  = threadIdx.x;
    const int lane = tid & 63;
    const int wid  = __builtin_amdgcn_readfirstlane(tid >> 6);
    const int l15  = lane & 15;
    const int g8   = (lane >> 4) * 8;

    const size_t blk_row0 = (size_t)blockIdx.x * ntiles * TROWS;

    // ---- prologue: issue x tile-0 loads first (HBM latency overlap) ----
    float4 xv[8];
    {
        const float4* xg = (const float4*)(x + blk_row0 * 256);
        #pragma unroll
        for (int c = 0; c < 8; ++c) xv[c] = xg[c * TPB + tid];
    }

    // ---- stage w1T as scaled f16 hi/lo (once) ----
    {
        const float4* wg = (const float4*)wz1;   // 4096 float4
        #pragma unroll
        for (int c = 0; c < 8; ++c) {
            const int q = c * TPB + tid;         // 0..4095
            const float4 v = wg[q];
            const int k = q >> 4, n0 = (q & 15) * 4;
            const float vv[4] = {v.x, v.y, v.z, v.w};
            #pragma unroll
            for (int i = 0; i < 4; ++i) {
                const float s = vv[i] * SCALE_W;
                const _Float16 h = (_Float16)s;
                w1h[(n0 + i) * WS + k] = h;
                w1l[(n0 + i) * WS + k] = (_Float16)(s - (float)h);
            }
        }
        if (tid < 256) {                         // w2T: 256 float4
            const float4 v = ((const float4*)wz2)[tid];
            const int k = tid >> 2, c0 = (tid & 3) * 4;
            const float vv[4] = {v.x, v.y, v.z, v.w};
            #pragma unroll
            for (int i = 0; i < 4; ++i) {
                const float s = vv[i] * SCALE_W;
                const _Float16 h = (_Float16)s;
                w2h[(c0 + i) * W2S + k] = h;
                w2l[(c0 + i) * W2S + k] = (_Float16)(s - (float)h);
            }
        }
    }

    // ---- per-lane constants ----
    const int rt  = wid >> 1;                 // rowtile 0..3 (layer 1)
    const int ntp = wid & 1;                  // col-pair 0..1
    const int col0 = (2 * ntp) * 16 + l15;
    const int col1 = (2 * ntp + 1) * 16 + l15;
    const float b1v0 = b1[col0], b1v1 = b1[col1];
    float b2v[4], w3v[4][4];
    #pragma unroll
    for (int i = 0; i < 4; ++i) {
        const int c2 = (lane >> 4) * 4 + i;
        b2v[i] = b2[c2];
        #pragma unroll
        for (int c3 = 0; c3 < 4; ++c3) w3v[i][c3] = wz3[c2 * 4 + c3];
    }
    const float b3v[4] = {b3[0], b3[1], b3[2], b3[3]};

    lds_barrier();   // weights staged

    // ---- persistent register fragments: w1 hi AND lo ----
    half8 Bh[8][2], Bl[8][2];
    #pragma unroll
    for (int kt = 0; kt < 8; ++kt) {
        Bh[kt][0] = *(const half8*)(w1h + col0 * WS + kt * 32 + g8);
        Bh[kt][1] = *(const half8*)(w1h + col1 * WS + kt * 32 + g8);
        Bl[kt][0] = *(const half8*)(w1l + col0 * WS + kt * 32 + g8);
        Bl[kt][1] = *(const half8*)(w1l + col1 * WS + kt * 32 + g8);
    }
    half8 A2h[2], A2l[2];                     // w2T A-frags (layer 2)
    #pragma unroll
    for (int kt = 0; kt < 2; ++kt) {
        A2h[kt] = *(const half8*)(w2h + l15 * W2S + kt * 32 + g8);
        A2l[kt] = *(const half8*)(w2l + l15 * W2S + kt * 32 + g8);
    }

    float local_sum = 0.f;

    for (int t = 0; t < ntiles; ++t) {
        // ---- convert regs -> LDS f16 hi/lo (row = c*8+wid, k = lane*4) ----
        #pragma unroll
        for (int c = 0; c < 8; ++c) {
            const float vv[4] = {xv[c].x, xv[c].y, xv[c].z, xv[c].w};
            half4 hh, hl;
            #pragma unroll
            for (int i = 0; i < 4; ++i) {
                const float s = vv[i] * SCALE_IN;
                const _Float16 h = (_Float16)s;
                hh[i] = h;
                hl[i] = (_Float16)(s - (float)h);
            }
            const int row = c * 8 + wid;
            *(half4*)(xh + row * XS + lane * 4) = hh;
            *(half4*)(xl + row * XS + lane * 4) = hl;
        }
        // ---- issue next-tile global loads (stay in flight across barrier) ----
        if (t + 1 < ntiles) {
            const float4* xg2 =
                (const float4*)(x + (blk_row0 + (size_t)(t + 1) * TROWS) * 256);
            #pragma unroll
            for (int c = 0; c < 8; ++c) xv[c] = xg2[c * TPB + tid];
        }
        lds_barrier();   // B1: x(t) visible

        // ---- layer 1: 3-term split MFMA; A from LDS, B from registers ----
        f32x4 acc0 = {0.f, 0.f, 0.f, 0.f}, acc1 = {0.f, 0.f, 0.f, 0.f};
        {
            const _Float16* xh_p = xh + (rt * 16 + l15) * XS;
            const _Float16* xl_p = xl + (rt * 16 + l15) * XS;
            #pragma unroll
            for (int kt = 0; kt < 8; ++kt) {
                const int ko = kt * 32 + g8;
                const half8 ah = *(const half8*)(xh_p + ko);
                const half8 al = *(const half8*)(xl_p + ko);
                acc0 = MFMA16(ah, Bh[kt][0], acc0);
                acc1 = MFMA16(ah, Bh[kt][1], acc1);
                acc0 = MFMA16(al, Bh[kt][0], acc0);
                acc1 = MFMA16(al, Bh[kt][1], acc1);
                acc0 = MFMA16(ah, Bl[kt][0], acc0);
                acc1 = MFMA16(ah, Bl[kt][1], acc1);
            }
        }
        // ---- epilogue: scale+bias+relu -> h1 f16 hi/lo ----
        #pragma unroll
        for (int i = 0; i < 4; ++i) {
            const int r = rt * 16 + (lane >> 4) * 4 + i;
            const float h0 = fmaxf(fmaf(acc0[i], INV_SC, b1v0), 0.f);
            const float h1f = fmaxf(fmaf(acc1[i], INV_SC, b1v1), 0.f);
            const float s0 = h0 * SCALE_IN;
            const _Float16 h0h = (_Float16)s0;
            h1h[r * H1S + col0] = h0h;
            h1l[r * H1S + col0] = (_Float16)(s0 - (float)h0h);
            const float s1 = h1f * SCALE_IN;
            const _Float16 h1hh = (_Float16)s1;
            h1h[r * H1S + col1] = h1hh;
            h1l[r * H1S + col1] = (_Float16)(s1 - (float)h1hh);
        }
        lds_barrier();   // B2: h1 ready

        // ---- layer 2 (MFMA) + layer 3 + exp: waves 0..3 ----
        if (wid < 4) {
            f32x4 a2 = {0.f, 0.f, 0.f, 0.f};
            const _Float16* hh_p = h1h + (wid * 16 + l15) * H1S;
            const _Float16* hl_p = h1l + (wid * 16 + l15) * H1S;
            #pragma unroll
            for (int kt = 0; kt < 2; ++kt) {
                const int ko = kt * 32 + g8;
                const half8 bh = *(const half8*)(hh_p + ko);
                const half8 bl = *(const half8*)(hl_p + ko);
                a2 = MFMA16(A2h[kt], bh, a2);
                a2 = MFMA16(A2l[kt], bh, a2);
                a2 = MFMA16(A2h[kt], bl, a2);
            }
            // lane holds h2pre for c2 = (lane>>4)*4+i, row = wid*16 + l15
            float p0 = 0.f, p1 = 0.f, p2 = 0.f, p3 = 0.f;
            #pragma unroll
            for (int i = 0; i < 4; ++i) {
                const float h2 = tanhf(fmaf(a2[i], INV_SC, b2v[i]));
                p0 = fmaf(h2, w3v[i][0], p0);
                p1 = fmaf(h2, w3v[i][1], p1);
                p2 = fmaf(h2, w3v[i][2], p2);
                p3 = fmaf(h2, w3v[i][3], p3);
            }
            p0 += __shfl_xor(p0, 16, 64); p0 += __shfl_xor(p0, 32, 64);
            p1 += __shfl_xor(p1, 16, 64); p1 += __shfl_xor(p1, 32, 64);
            p2 += __shfl_xor(p2, 16, 64); p2 += __shfl_xor(p2, 32, 64);
            p3 += __shfl_xor(p3, 16, 64); p3 += __shfl_xor(p3, 32, 64);
            if (lane < 16) {
                const float e0 = expf(p0 + b3v[0]);
                const float e1 = expf(p1 + b3v[1]);
                const float e2 = expf(p2 + b3v[2]);
                const float e3 = expf(p3 + b3v[3]);
                const size_t row = blk_row0 + (size_t)t * TROWS + wid * 16 + lane;
                float4 ev; ev.x = e0; ev.y = e1; ev.z = e2; ev.w = e3;
                *(float4*)(Eout + row * 4) = ev;
                local_sum += (e0 + e1) + (e2 + e3);
            }
        }
    }

    // ---- block exp-sum reduction (deterministic) ----
    #pragma unroll
    for (int off = 32; off > 0; off >>= 1)
        local_sum += __shfl_down(local_sum, off, 64);
    if (lane == 0) sums[wid] = local_sum;
    lds_barrier();
    if (tid == 0) {
        float s = 0.f;
        #pragma unroll
        for (int w = 0; w < 8; ++w) s += sums[w];
        block_sums[blockIdx.x] = s;
    }
    __threadfence();

    // ---- grid-wide sync, then in-kernel softmax scale ----
    cg::this_grid().sync();

    {
        float s = 0.f;
        if (wid < 4) s = block_sums[(wid << 6) | lane];
        #pragma unroll
        for (int off = 32; off > 0; off >>= 1) s += __shfl_down(s, off, 64);
        if (wid < 4 && lane == 0) sums[wid] = s;
        lds_barrier();
        const float inv = 1.0f / ((sums[0] + sums[1]) + (sums[2] + sums[3]));

        // scale own E chunk: 1024 float4 per block (L2/L3-hot, own rows)
        float4* o4 = (float4*)Eout;
        const size_t base = blk_row0;   // 1 float4 per row
        #pragma unroll
        for (int i = 0; i < 2; ++i) {
            const size_t idx = base + (size_t)i * TPB + tid;
            float4 v = o4[idx];
            v.x *= inv; v.y *= inv; v.z *= inv; v.w *= inv;
            o4[idx] = v;
        }
    }
}

extern "C" void kernel_launch(void* const* d_in, const int* in_sizes, int n_in,
                              void* d_out, int out_size, void* d_ws, size_t ws_size,
                              hipStream_t stream) {
    (void)n_in; (void)ws_size; (void)out_size;
    const float* x   = (const float*)d_in[0];
    const float* wz1 = (const float*)d_in[1];
    const float* b1  = (const float*)d_in[2];
    const float* wz2 = (const float*)d_in[3];
    const float* b2  = (const float*)d_in[4];
    const float* wz3 = (const float*)d_in[5];
    const float* b3  = (const float*)d_in[6];
    float* out = (float*)d_out;

    float* block_sums = (float*)d_ws;            // GRID floats

    const int B = in_sizes[0] / 256;             // 262144
    int ntiles = B / (GRID * TROWS);             // 16

    hipFuncSetAttribute((const void*)fused_mlp,
                        hipFuncAttributeMaxDynamicSharedMemorySize, SMEM_BYTES);

    void* args[] = {(void*)&x, (void*)&wz1, (void*)&b1, (void*)&wz2,
                    (void*)&b2, (void*)&wz3, (void*)&b3,
                    (void*)&out, (void*)&block_sums, (void*)&ntiles};
    hipLaunchCooperativeKernel((const void*)fused_mlp, dim3(GRID), dim3(TPB),
                               args, SMEM_BYTES, stream);
}

// Round 9
// 95.729 us; speedup vs baseline: 1.4954x; 1.4183x over previous
//
#include <hip/hip_runtime.h>

// B = 262144 rows, 256 -> 64 (relu) -> 16 (tanh) -> 4 -> global softmax.
// Layer 1 & 2 on MFMA f16 with 2-way split operands (3-term products),
// power-of-2 scaled so split residuals stay f16-normal.
// R9: exact R5 kernel body + hand-rolled atomic grid barrier (NO cooperative
//     groups call -> no outlined callee -> no VGPR cap/spill) + in-kernel
//     softmax scale. Counter zeroed per call via hipMemsetAsync.

typedef _Float16 half8 __attribute__((ext_vector_type(8)));
typedef _Float16 half4 __attribute__((ext_vector_type(4)));
typedef float f32x4 __attribute__((ext_vector_type(4)));

#define GRID 256
#define TPB  512
#define TROWS 64

#define XS  264   // f16 stride for x rows (256 + 8 pad)
#define WS  264   // w1T stride
#define H1S 72    // h1 [row][j] stride (64 + 8)
#define W2S 72    // w2T stride

#define SCALE_IN 256.0f            // 2^8
#define SCALE_W  2048.0f           // 2^11
#define INV_SC   (1.0f/524288.0f)  // 2^-19

// ---- LDS byte offsets (R3/R5 layout) ----
#define OFF_XH  0
#define OFF_XL  (OFF_XH + TROWS*XS*2)      // 33792
#define OFF_W1H (OFF_XL + TROWS*XS*2)      // 67584
#define OFF_W1L (OFF_W1H + 64*WS*2)        // 101376
#define OFF_H1H (OFF_W1L + 64*WS*2)        // 135168
#define OFF_H1L (OFF_H1H + TROWS*H1S*2)    // 144384
#define OFF_W2H (OFF_H1L + TROWS*H1S*2)    // 153600
#define OFF_W2L (OFF_W2H + 16*W2S*2)       // 155904
#define OFF_SUM (OFF_W2L + 16*W2S*2)       // 158208
#define SMEM_BYTES (OFF_SUM + 64*4)        // 158464 <= 163840 -> 1 block/CU

extern __shared__ char smem_raw[];

#define MFMA16(a,b,c) __builtin_amdgcn_mfma_f32_16x16x32_f16((a),(b),(c),0,0,0)

__device__ __forceinline__ void lds_barrier() {
    asm volatile("s_waitcnt lgkmcnt(0)\ns_barrier" ::: "memory");
}

__global__ __launch_bounds__(TPB, 2) void fused_mlp(
    const float* __restrict__ x,
    const float* __restrict__ wz1, const float* __restrict__ b1,
    const float* __restrict__ wz2, const float* __restrict__ b2,
    const float* __restrict__ wz3, const float* __restrict__ b3,
    float* __restrict__ Eout, float* __restrict__ block_sums,
    unsigned* __restrict__ counter, int ntiles)
{
    _Float16* xh  = (_Float16*)(smem_raw + OFF_XH);
    _Float16* xl  = (_Float16*)(smem_raw + OFF_XL);
    _Float16* w1h = (_Float16*)(smem_raw + OFF_W1H);
    _Float16* w1l = (_Float16*)(smem_raw + OFF_W1L);
    _Float16* h1h = (_Float16*)(smem_raw + OFF_H1H);
    _Float16* h1l = (_Float16*)(smem_raw + OFF_H1L);
    _Float16* w2h = (_Float16*)(smem_raw + OFF_W2H);
    _Float16* w2l = (_Float16*)(smem_raw + OFF_W2L);
    float* sums   = (float*)(smem_raw + OFF_SUM);

    const int tid  = threadIdx.x;
    const int lane = tid & 63;
    const int wid  = __builtin_amdgcn_readfirstlane(tid >> 6);
    const int l15  = lane & 15;
    const int g8   = (lane >> 4) * 8;

    const size_t blk_row0 = (size_t)blockIdx.x * ntiles * TROWS;

    // ---- prologue: issue x tile-0 loads first (HBM latency overlap) ----
    float4 xv[8];
    {
        const float4* xg = (const float4*)(x + blk_row0 * 256);
        #pragma unroll
        for (int c = 0; c < 8; ++c) xv[c] = xg[c * TPB + tid];
    }

    // ---- stage w1T as scaled f16 hi/lo (once) ----
    {
        const float4* wg = (const float4*)wz1;   // 4096 float4
        #pragma unroll
        for (int c = 0; c < 8; ++c) {
            const int q = c * TPB + tid;         // 0..4095
            const float4 v = wg[q];
            const int k = q >> 4, n0 = (q & 15) * 4;
            const float vv[4] = {v.x, v.y, v.z, v.w};
            #pragma unroll
            for (int i = 0; i < 4; ++i) {
                const float s = vv[i] * SCALE_W;
                const _Float16 h = (_Float16)s;
                w1h[(n0 + i) * WS + k] = h;
                w1l[(n0 + i) * WS + k] = (_Float16)(s - (float)h);
            }
        }
        if (tid < 256) {                         // w2T: 256 float4
            const float4 v = ((const float4*)wz2)[tid];
            const int k = tid >> 2, c0 = (tid & 3) * 4;
            const float vv[4] = {v.x, v.y, v.z, v.w};
            #pragma unroll
            for (int i = 0; i < 4; ++i) {
                const float s = vv[i] * SCALE_W;
                const _Float16 h = (_Float16)s;
                w2h[(c0 + i) * W2S + k] = h;
                w2l[(c0 + i) * W2S + k] = (_Float16)(s - (float)h);
            }
        }
    }

    // ---- per-lane constants ----
    const int rt  = wid >> 1;                 // rowtile 0..3 (layer 1)
    const int ntp = wid & 1;                  // col-pair 0..1
    const int col0 = (2 * ntp) * 16 + l15;
    const int col1 = (2 * ntp + 1) * 16 + l15;
    const float b1v0 = b1[col0], b1v1 = b1[col1];
    float b2v[4], w3v[4][4];
    #pragma unroll
    for (int i = 0; i < 4; ++i) {
        const int c2 = (lane >> 4) * 4 + i;
        b2v[i] = b2[c2];
        #pragma unroll
        for (int c3 = 0; c3 < 4; ++c3) w3v[i][c3] = wz3[c2 * 4 + c3];
    }
    const float b3v[4] = {b3[0], b3[1], b3[2], b3[3]};

    lds_barrier();   // weights staged

    // ---- persistent register fragments: w1 hi AND lo ----
    half8 Bh[8][2], Bl[8][2];
    #pragma unroll
    for (int kt = 0; kt < 8; ++kt) {
        Bh[kt][0] = *(const half8*)(w1h + col0 * WS + kt * 32 + g8);
        Bh[kt][1] = *(const half8*)(w1h + col1 * WS + kt * 32 + g8);
        Bl[kt][0] = *(const half8*)(w1l + col0 * WS + kt * 32 + g8);
        Bl[kt][1] = *(const half8*)(w1l + col1 * WS + kt * 32 + g8);
    }
    half8 A2h[2], A2l[2];                     // w2T A-frags (layer 2)
    #pragma unroll
    for (int kt = 0; kt < 2; ++kt) {
        A2h[kt] = *(const half8*)(w2h + l15 * W2S + kt * 32 + g8);
        A2l[kt] = *(const half8*)(w2l + l15 * W2S + kt * 32 + g8);
    }

    float local_sum = 0.f;

    for (int t = 0; t < ntiles; ++t) {
        // ---- convert regs -> LDS f16 hi/lo (row = c*8+wid, k = lane*4) ----
        #pragma unroll
        for (int c = 0; c < 8; ++c) {
            const float vv[4] = {xv[c].x, xv[c].y, xv[c].z, xv[c].w};
            half4 hh, hl;
            #pragma unroll
            for (int i = 0; i < 4; ++i) {
                const float s = vv[i] * SCALE_IN;
                const _Float16 h = (_Float16)s;
                hh[i] = h;
                hl[i] = (_Float16)(s - (float)h);
            }
            const int row = c * 8 + wid;
            *(half4*)(xh + row * XS + lane * 4) = hh;
            *(half4*)(xl + row * XS + lane * 4) = hl;
        }
        // ---- issue next-tile global loads (stay in flight across barrier) ----
        if (t + 1 < ntiles) {
            const float4* xg2 =
                (const float4*)(x + (blk_row0 + (size_t)(t + 1) * TROWS) * 256);
            #pragma unroll
            for (int c = 0; c < 8; ++c) xv[c] = xg2[c * TPB + tid];
        }
        lds_barrier();   // B1: x(t) visible

        // ---- layer 1: 3-term split MFMA; A from LDS, B from registers ----
        f32x4 acc0 = {0.f, 0.f, 0.f, 0.f}, acc1 = {0.f, 0.f, 0.f, 0.f};
        {
            const _Float16* xh_p = xh + (rt * 16 + l15) * XS;
            const _Float16* xl_p = xl + (rt * 16 + l15) * XS;
            #pragma unroll
            for (int kt = 0; kt < 8; ++kt) {
                const int ko = kt * 32 + g8;
                const half8 ah = *(const half8*)(xh_p + ko);
                const half8 al = *(const half8*)(xl_p + ko);
                acc0 = MFMA16(ah, Bh[kt][0], acc0);
                acc1 = MFMA16(ah, Bh[kt][1], acc1);
                acc0 = MFMA16(al, Bh[kt][0], acc0);
                acc1 = MFMA16(al, Bh[kt][1], acc1);
                acc0 = MFMA16(ah, Bl[kt][0], acc0);
                acc1 = MFMA16(ah, Bl[kt][1], acc1);
            }
        }
        // ---- epilogue: scale+bias+relu -> h1 f16 hi/lo ----
        #pragma unroll
        for (int i = 0; i < 4; ++i) {
            const int r = rt * 16 + (lane >> 4) * 4 + i;
            const float h0 = fmaxf(fmaf(acc0[i], INV_SC, b1v0), 0.f);
            const float h1f = fmaxf(fmaf(acc1[i], INV_SC, b1v1), 0.f);
            const float s0 = h0 * SCALE_IN;
            const _Float16 h0h = (_Float16)s0;
            h1h[r * H1S + col0] = h0h;
            h1l[r * H1S + col0] = (_Float16)(s0 - (float)h0h);
            const float s1 = h1f * SCALE_IN;
            const _Float16 h1hh = (_Float16)s1;
            h1h[r * H1S + col1] = h1hh;
            h1l[r * H1S + col1] = (_Float16)(s1 - (float)h1hh);
        }
        lds_barrier();   // B2: h1 ready

        // ---- layer 2 (MFMA) + layer 3 + exp: waves 0..3 ----
        if (wid < 4) {
            f32x4 a2 = {0.f, 0.f, 0.f, 0.f};
            const _Float16* hh_p = h1h + (wid * 16 + l15) * H1S;
            const _Float16* hl_p = h1l + (wid * 16 + l15) * H1S;
            #pragma unroll
            for (int kt = 0; kt < 2; ++kt) {
                const int ko = kt * 32 + g8;
                const half8 bh = *(const half8*)(hh_p + ko);
                const half8 bl = *(const half8*)(hl_p + ko);
                a2 = MFMA16(A2h[kt], bh, a2);
                a2 = MFMA16(A2l[kt], bh, a2);
                a2 = MFMA16(A2h[kt], bl, a2);
            }
            // lane holds h2pre for c2 = (lane>>4)*4+i, row = wid*16 + l15
            float p0 = 0.f, p1 = 0.f, p2 = 0.f, p3 = 0.f;
            #pragma unroll
            for (int i = 0; i < 4; ++i) {
                const float h2 = tanhf(fmaf(a2[i], INV_SC, b2v[i]));
                p0 = fmaf(h2, w3v[i][0], p0);
                p1 = fmaf(h2, w3v[i][1], p1);
                p2 = fmaf(h2, w3v[i][2], p2);
                p3 = fmaf(h2, w3v[i][3], p3);
            }
            p0 += __shfl_xor(p0, 16, 64); p0 += __shfl_xor(p0, 32, 64);
            p1 += __shfl_xor(p1, 16, 64); p1 += __shfl_xor(p1, 32, 64);
            p2 += __shfl_xor(p2, 16, 64); p2 += __shfl_xor(p2, 32, 64);
            p3 += __shfl_xor(p3, 16, 64); p3 += __shfl_xor(p3, 32, 64);
            if (lane < 16) {
                const float e0 = expf(p0 + b3v[0]);
                const float e1 = expf(p1 + b3v[1]);
                const float e2 = expf(p2 + b3v[2]);
                const float e3 = expf(p3 + b3v[3]);
                const size_t row = blk_row0 + (size_t)t * TROWS + wid * 16 + lane;
                float4 ev; ev.x = e0; ev.y = e1; ev.z = e2; ev.w = e3;
                *(float4*)(Eout + row * 4) = ev;
                local_sum += (e0 + e1) + (e2 + e3);
            }
        }
    }

    // ---- block exp-sum reduction (deterministic) ----
    #pragma unroll
    for (int off = 32; off > 0; off >>= 1)
        local_sum += __shfl_down(local_sum, off, 64);
    if (lane == 0) sums[wid] = local_sum;
    lds_barrier();

    // ---- hand-rolled grid barrier (no outlined call; inline atomics) ----
    if (tid == 0) {
        float s = 0.f;
        #pragma unroll
        for (int w = 0; w < 8; ++w) s += sums[w];
        block_sums[blockIdx.x] = s;
        __threadfence();                         // release partial sum
        atomicAdd(counter, 1u);
        while (__hip_atomic_load(counter, __ATOMIC_ACQUIRE,
                                 __HIP_MEMORY_SCOPE_AGENT) < (unsigned)GRID) {
            __builtin_amdgcn_s_sleep(2);
        }
    }
    __syncthreads();

    // ---- re-reduce the 256 partials (agent-scope loads), then scale E ----
    {
        float s = 0.f;
        if (wid < 4)
            s = __hip_atomic_load(&block_sums[(wid << 6) | lane],
                                  __ATOMIC_RELAXED, __HIP_MEMORY_SCOPE_AGENT);
        #pragma unroll
        for (int off = 32; off > 0; off >>= 1) s += __shfl_down(s, off, 64);
        if (wid < 4 && lane == 0) sums[wid] = s;
        lds_barrier();
        const float inv = 1.0f / ((sums[0] + sums[1]) + (sums[2] + sums[3]));

        // scale own E chunk: 1024 float4 per block (cache-hot, own rows)
        float4* o4 = (float4*)Eout;
        #pragma unroll
        for (int i = 0; i < 2; ++i) {
            const size_t idx = blk_row0 + (size_t)i * TPB + tid;
            float4 v = o4[idx];
            v.x *= inv; v.y *= inv; v.z *= inv; v.w *= inv;
            o4[idx] = v;
        }
    }
}

extern "C" void kernel_launch(void* const* d_in, const int* in_sizes, int n_in,
                              void* d_out, int out_size, void* d_ws, size_t ws_size,
                              hipStream_t stream) {
    (void)n_in; (void)ws_size; (void)out_size;
    const float* x   = (const float*)d_in[0];
    const float* wz1 = (const float*)d_in[1];
    const float* b1  = (const float*)d_in[2];
    const float* wz2 = (const float*)d_in[3];
    const float* b2  = (const float*)d_in[4];
    const float* wz3 = (const float*)d_in[5];
    const float* b3  = (const float*)d_in[6];
    float* out = (float*)d_out;

    float* block_sums = (float*)d_ws;                   // GRID floats
    unsigned* counter = (unsigned*)((float*)d_ws + GRID);

    const int B = in_sizes[0] / 256;             // 262144
    int ntiles = B / (GRID * TROWS);             // 16

    hipMemsetAsync(counter, 0, sizeof(unsigned), stream);   // capture-safe

    hipFuncSetAttribute((const void*)fused_mlp,
                        hipFuncAttributeMaxDynamicSharedMemorySize, SMEM_BYTES);

    void* args[] = {(void*)&x, (void*)&wz1, (void*)&b1, (void*)&wz2,
                    (void*)&b2, (void*)&wz3, (void*)&b3,
                    (void*)&out, (void*)&block_sums, (void*)&counter,
                    (void*)&ntiles};
    hipLaunchCooperativeKernel((const void*)fused_mlp, dim3(GRID), dim3(TPB),
                               args, SMEM_BYTES, stream);
}

// Round 10
// 64.262 us; speedup vs baseline: 2.2277x; 1.4897x over previous
//
#include <hip/hip_runtime.h>

// B = 262144 rows, 256 -> 64 (relu) -> 16 (tanh) -> 4 -> global softmax.
// Layer 1 & 2 on MFMA f16 with 2-way split operands (3-term products),
// power-of-2 scaled so split residuals stay f16-normal.
// R10: R5 two-kernel structure + double-buffered xv prefetch implemented
//      with named buffers and macro-duplicated tile bodies (no lambda, no
//      runtime indexing -> registers stay registers). Bl from LDS (R3-proven)
//      to keep VGPR < 256 at 2 waves/SIMD.

typedef _Float16 half8 __attribute__((ext_vector_type(8)));
typedef _Float16 half4 __attribute__((ext_vector_type(4)));
typedef float f32x4 __attribute__((ext_vector_type(4)));

#define GRID 256
#define TPB  512
#define TROWS 64

#define XS  264   // f16 stride for x rows (256 + 8 pad)
#define WS  264   // w1T stride
#define H1S 72    // h1 [row][j] stride (64 + 8)
#define W2S 72    // w2T stride

#define SCALE_IN 256.0f            // 2^8
#define SCALE_W  2048.0f           // 2^11
#define INV_SC   (1.0f/524288.0f)  // 2^-19

// ---- LDS byte offsets (R3/R5 layout) ----
#define OFF_XH  0
#define OFF_XL  (OFF_XH + TROWS*XS*2)      // 33792
#define OFF_W1H (OFF_XL + TROWS*XS*2)      // 67584
#define OFF_W1L (OFF_W1H + 64*WS*2)        // 101376
#define OFF_H1H (OFF_W1L + 64*WS*2)        // 135168
#define OFF_H1L (OFF_H1H + TROWS*H1S*2)    // 144384
#define OFF_W2H (OFF_H1L + TROWS*H1S*2)    // 153600
#define OFF_W2L (OFF_W2H + 16*W2S*2)       // 155904
#define OFF_SUM (OFF_W2L + 16*W2S*2)       // 158208
#define SMEM_BYTES (OFF_SUM + 64*4)        // 158464 <= 163840 -> 1 block/CU

extern __shared__ char smem_raw[];

#define MFMA16(a,b,c) __builtin_amdgcn_mfma_f32_16x16x32_f16((a),(b),(c),0,0,0)

__device__ __forceinline__ void lds_barrier() {
    asm volatile("s_waitcnt lgkmcnt(0)\ns_barrier" ::: "memory");
}

// One tile iteration. CUR holds x(T) (loaded one tile ago); at the top we
// issue x(T+1) into NXT so the HBM queue never goes empty.
#define TILE_BODY(CUR, NXT, T)                                                \
    {                                                                         \
        const int t = (T);                                                    \
        if (t + 1 < ntiles) {                                                 \
            const float4* xg2 =                                               \
                (const float4*)(x + (blk_row0 + (size_t)(t + 1) * TROWS) * 256);\
            _Pragma("unroll")                                                 \
            for (int c = 0; c < 8; ++c) NXT[c] = xg2[c * TPB + tid];          \
        }                                                                     \
        _Pragma("unroll")                                                     \
        for (int c = 0; c < 8; ++c) {                                         \
            const float vv[4] = {CUR[c].x, CUR[c].y, CUR[c].z, CUR[c].w};     \
            half4 hh, hl;                                                     \
            _Pragma("unroll")                                                 \
            for (int i = 0; i < 4; ++i) {                                     \
                const float s = vv[i] * SCALE_IN;                             \
                const _Float16 h = (_Float16)s;                               \
                hh[i] = h;                                                    \
                hl[i] = (_Float16)(s - (float)h);                             \
            }                                                                 \
            const int row = c * 8 + wid;                                      \
            *(half4*)(xh + row * XS + lane * 4) = hh;                         \
            *(half4*)(xl + row * XS + lane * 4) = hl;                         \
        }                                                                     \
        lds_barrier(); /* B1: x(t) visible */                                 \
        f32x4 acc0 = {0.f, 0.f, 0.f, 0.f}, acc1 = {0.f, 0.f, 0.f, 0.f};       \
        {                                                                     \
            const _Float16* xh_p = xh + (rt * 16 + l15) * XS;                 \
            const _Float16* xl_p = xl + (rt * 16 + l15) * XS;                 \
            const _Float16* wl_p0 = w1l + col0 * WS;                          \
            const _Float16* wl_p1 = w1l + col1 * WS;                          \
            _Pragma("unroll")                                                 \
            for (int kt = 0; kt < 8; ++kt) {                                  \
                const int ko = kt * 32 + g8;                                  \
                const half8 ah  = *(const half8*)(xh_p + ko);                 \
                const half8 al  = *(const half8*)(xl_p + ko);                 \
                const half8 bl0 = *(const half8*)(wl_p0 + ko);                \
                const half8 bl1 = *(const half8*)(wl_p1 + ko);                \
                acc0 = MFMA16(ah, Bh[kt][0], acc0);                           \
                acc1 = MFMA16(ah, Bh[kt][1], acc1);                           \
                acc0 = MFMA16(al, Bh[kt][0], acc0);                           \
                acc1 = MFMA16(al, Bh[kt][1], acc1);                           \
                acc0 = MFMA16(ah, bl0, acc0);                                 \
                acc1 = MFMA16(ah, bl1, acc1);                                 \
            }                                                                 \
        }                                                                     \
        _Pragma("unroll")                                                     \
        for (int i = 0; i < 4; ++i) {                                         \
            const int r = rt * 16 + (lane >> 4) * 4 + i;                      \
            const float h0 = fmaxf(fmaf(acc0[i], INV_SC, b1v0), 0.f);         \
            const float h1f = fmaxf(fmaf(acc1[i], INV_SC, b1v1), 0.f);        \
            const float s0 = h0 * SCALE_IN;                                   \
            const _Float16 h0h = (_Float16)s0;                                \
            h1h[r * H1S + col0] = h0h;                                        \
            h1l[r * H1S + col0] = (_Float16)(s0 - (float)h0h);                \
            const float s1 = h1f * SCALE_IN;                                  \
            const _Float16 h1hh = (_Float16)s1;                               \
            h1h[r * H1S + col1] = h1hh;                                       \
            h1l[r * H1S + col1] = (_Float16)(s1 - (float)h1hh);               \
        }                                                                     \
        lds_barrier(); /* B2: h1 ready */                                     \
        if (wid < 4) {                                                        \
            f32x4 a2 = {0.f, 0.f, 0.f, 0.f};                                  \
            const _Float16* hh_p = h1h + (wid * 16 + l15) * H1S;              \
            const _Float16* hl_p = h1l + (wid * 16 + l15) * H1S;              \
            _Pragma("unroll")                                                 \
            for (int kt = 0; kt < 2; ++kt) {                                  \
                const int ko = kt * 32 + g8;                                  \
                const half8 bh = *(const half8*)(hh_p + ko);                  \
                const half8 bl = *(const half8*)(hl_p + ko);                  \
                a2 = MFMA16(A2h[kt], bh, a2);                                 \
                a2 = MFMA16(A2l[kt], bh, a2);                                 \
                a2 = MFMA16(A2h[kt], bl, a2);                                 \
            }                                                                 \
            float p0 = 0.f, p1 = 0.f, p2 = 0.f, p3 = 0.f;                     \
            _Pragma("unroll")                                                 \
            for (int i = 0; i < 4; ++i) {                                     \
                const float h2 = tanhf(fmaf(a2[i], INV_SC, b2v[i]));          \
                p0 = fmaf(h2, w3v[i][0], p0);                                 \
                p1 = fmaf(h2, w3v[i][1], p1);                                 \
                p2 = fmaf(h2, w3v[i][2], p2);                                 \
                p3 = fmaf(h2, w3v[i][3], p3);                                 \
            }                                                                 \
            p0 += __shfl_xor(p0, 16, 64); p0 += __shfl_xor(p0, 32, 64);       \
            p1 += __shfl_xor(p1, 16, 64); p1 += __shfl_xor(p1, 32, 64);       \
            p2 += __shfl_xor(p2, 16, 64); p2 += __shfl_xor(p2, 32, 64);       \
            p3 += __shfl_xor(p3, 16, 64); p3 += __shfl_xor(p3, 32, 64);       \
            if (lane < 16) {                                                  \
                const float e0 = expf(p0 + b3v[0]);                           \
                const float e1 = expf(p1 + b3v[1]);                           \
                const float e2 = expf(p2 + b3v[2]);                           \
                const float e3 = expf(p3 + b3v[3]);                           \
                const size_t row = blk_row0 + (size_t)t * TROWS + wid * 16 + lane;\
                float4 ev; ev.x = e0; ev.y = e1; ev.z = e2; ev.w = e3;        \
                *(float4*)(Eout + row * 4) = ev;                              \
                local_sum += (e0 + e1) + (e2 + e3);                           \
            }                                                                 \
        }                                                                     \
    }

__global__ __launch_bounds__(TPB, 2) void fused_mlp(
    const float* __restrict__ x,
    const float* __restrict__ wz1, const float* __restrict__ b1,
    const float* __restrict__ wz2, const float* __restrict__ b2,
    const float* __restrict__ wz3, const float* __restrict__ b3,
    float* __restrict__ Eout, float* __restrict__ block_sums,
    int ntiles)
{
    _Float16* xh  = (_Float16*)(smem_raw + OFF_XH);
    _Float16* xl  = (_Float16*)(smem_raw + OFF_XL);
    _Float16* w1h = (_Float16*)(smem_raw + OFF_W1H);
    _Float16* w1l = (_Float16*)(smem_raw + OFF_W1L);
    _Float16* h1h = (_Float16*)(smem_raw + OFF_H1H);
    _Float16* h1l = (_Float16*)(smem_raw + OFF_H1L);
    _Float16* w2h = (_Float16*)(smem_raw + OFF_W2H);
    _Float16* w2l = (_Float16*)(smem_raw + OFF_W2L);
    float* sums   = (float*)(smem_raw + OFF_SUM);

    const int tid  = threadIdx.x;
    const int lane = tid & 63;
    const int wid  = __builtin_amdgcn_readfirstlane(tid >> 6);
    const int l15  = lane & 15;
    const int g8   = (lane >> 4) * 8;

    const size_t blk_row0 = (size_t)blockIdx.x * ntiles * TROWS;

    // ---- prologue: issue x tile-0 loads first (HBM latency overlap) ----
    float4 xva[8], xvb[8];
    {
        const float4* xg = (const float4*)(x + blk_row0 * 256);
        #pragma unroll
        for (int c = 0; c < 8; ++c) xva[c] = xg[c * TPB + tid];
    }

    // ---- stage w1T as scaled f16 hi/lo (once) ----
    {
        const float4* wg = (const float4*)wz1;   // 4096 float4
        #pragma unroll
        for (int c = 0; c < 8; ++c) {
            const int q = c * TPB + tid;         // 0..4095
            const float4 v = wg[q];
            const int k = q >> 4, n0 = (q & 15) * 4;
            const float vv[4] = {v.x, v.y, v.z, v.w};
            #pragma unroll
            for (int i = 0; i < 4; ++i) {
                const float s = vv[i] * SCALE_W;
                const _Float16 h = (_Float16)s;
                w1h[(n0 + i) * WS + k] = h;
                w1l[(n0 + i) * WS + k] = (_Float16)(s - (float)h);
            }
        }
        if (tid < 256) {                         // w2T: 256 float4
            const float4 v = ((const float4*)wz2)[tid];
            const int k = tid >> 2, c0 = (tid & 3) * 4;
            const float vv[4] = {v.x, v.y, v.z, v.w};
            #pragma unroll
            for (int i = 0; i < 4; ++i) {
                const float s = vv[i] * SCALE_W;
                const _Float16 h = (_Float16)s;
                w2h[(c0 + i) * W2S + k] = h;
                w2l[(c0 + i) * W2S + k] = (_Float16)(s - (float)h);
            }
        }
    }

    // ---- per-lane constants ----
    const int rt  = wid >> 1;                 // rowtile 0..3 (layer 1)
    const int ntp = wid & 1;                  // col-pair 0..1
    const int col0 = (2 * ntp) * 16 + l15;
    const int col1 = (2 * ntp + 1) * 16 + l15;
    const float b1v0 = b1[col0], b1v1 = b1[col1];
    float b2v[4], w3v[4][4];
    #pragma unroll
    for (int i = 0; i < 4; ++i) {
        const int c2 = (lane >> 4) * 4 + i;
        b2v[i] = b2[c2];
        #pragma unroll
        for (int c3 = 0; c3 < 4; ++c3) w3v[i][c3] = wz3[c2 * 4 + c3];
    }
    const float b3v[4] = {b3[0], b3[1], b3[2], b3[3]};

    lds_barrier();   // weights staged

    // ---- persistent register fragments: w1 hi (lo stays in LDS) ----
    half8 Bh[8][2];
    #pragma unroll
    for (int kt = 0; kt < 8; ++kt) {
        Bh[kt][0] = *(const half8*)(w1h + col0 * WS + kt * 32 + g8);
        Bh[kt][1] = *(const half8*)(w1h + col1 * WS + kt * 32 + g8);
    }
    half8 A2h[2], A2l[2];                     // w2T A-frags (layer 2)
    #pragma unroll
    for (int kt = 0; kt < 2; ++kt) {
        A2h[kt] = *(const half8*)(w2h + l15 * W2S + kt * 32 + g8);
        A2l[kt] = *(const half8*)(w2l + l15 * W2S + kt * 32 + g8);
    }

    float local_sum = 0.f;

    for (int tp = 0; tp < ntiles; tp += 2) {   // ntiles even
        TILE_BODY(xva, xvb, tp)
        TILE_BODY(xvb, xva, tp + 1)
    }

    // ---- block exp-sum reduction (deterministic) ----
    #pragma unroll
    for (int off = 32; off > 0; off >>= 1)
        local_sum += __shfl_down(local_sum, off, 64);
    if (lane == 0) sums[wid] = local_sum;
    lds_barrier();
    if (tid == 0) {
        float s = 0.f;
        #pragma unroll
        for (int w = 0; w < 8; ++w) s += sums[w];
        block_sums[blockIdx.x] = s;
    }
}

// Merged reduce+scale: every block deterministically re-reduces the 256
// partials (1 KiB, L2-hot), then scales its own chunk of E.
__global__ __launch_bounds__(256) void scale_kernel(
    float* __restrict__ out, const float* __restrict__ block_sums)
{
    __shared__ float red[4];
    const int tid = threadIdx.x;
    float s = block_sums[tid];
    #pragma unroll
    for (int off = 32; off > 0; off >>= 1) s += __shfl_down(s, off, 64);
    if ((tid & 63) == 0) red[tid >> 6] = s;
    __syncthreads();
    const float inv = 1.0f / ((red[0] + red[1]) + (red[2] + red[3]));
    const int idx = blockIdx.x * 256 + tid;
    float4* o4 = (float4*)out;
    float4 v = o4[idx];
    v.x *= inv; v.y *= inv; v.z *= inv; v.w *= inv;
    o4[idx] = v;
}

extern "C" void kernel_launch(void* const* d_in, const int* in_sizes, int n_in,
                              void* d_out, int out_size, void* d_ws, size_t ws_size,
                              hipStream_t stream) {
    (void)n_in; (void)ws_size;
    const float* x   = (const float*)d_in[0];
    const float* wz1 = (const float*)d_in[1];
    const float* b1  = (const float*)d_in[2];
    const float* wz2 = (const float*)d_in[3];
    const float* b2  = (const float*)d_in[4];
    const float* wz3 = (const float*)d_in[5];
    const float* b3  = (const float*)d_in[6];
    float* out = (float*)d_out;

    float* block_sums = (float*)d_ws;            // GRID floats

    const int B = in_sizes[0] / 256;             // 262144
    const int ntiles = B / (GRID * TROWS);       // 16

    hipFuncSetAttribute((const void*)fused_mlp,
                        hipFuncAttributeMaxDynamicSharedMemorySize, SMEM_BYTES);

    fused_mlp<<<GRID, TPB, SMEM_BYTES, stream>>>(
        x, wz1, b1, wz2, b2, wz3, b3, out, block_sums, ntiles);

    const int n4 = out_size / 4;                 // 262144
    scale_kernel<<<n4 / 256, 256, 0, stream>>>(out, block_sums);
}

// Round 11
// 57.270 us; speedup vs baseline: 2.4997x; 1.1221x over previous
//
#include <hip/hip_runtime.h>

// B = 262144 rows, 256 -> 64 (relu) -> 16 (tanh) -> 4 -> global softmax.
// Layer 1 & 2 on MFMA f16 with 2-way split operands (3-term products),
// power-of-2 scaled so split residuals stay f16-normal.
// R11: exact restoration of R5 (best verified: 57.4 us total).
//   - fused kernel: x -> regs -> convert phase -> f16 hi/lo LDS -> pure
//     ds_read+MFMA layer-1 loop; w1 hi+lo fragments persistent in registers;
//     layer 2 MFMA from LDS h1; layer 3 + exp in-register, shfl reduce.
//   - merged reduce+scale second kernel (each block re-reduces 256 partials).
// Rounds 6-10 showed: barrier-domain split, cooperative-launch fold (VGPR cap
// via cg call), hand-rolled grid barrier, and early-issue double-buffered
// prefetch ALL regress vs this structure. Do not reintroduce without new
// evidence (counted-vmcnt pipelining at source level failed 3x here).

typedef _Float16 half8 __attribute__((ext_vector_type(8)));
typedef _Float16 half4 __attribute__((ext_vector_type(4)));
typedef float f32x4 __attribute__((ext_vector_type(4)));

#define GRID 256
#define TPB  512
#define TROWS 64

#define XS  264   // f16 stride for x rows (256 + 8 pad)
#define WS  264   // w1T stride
#define H1S 72    // h1 [row][j] stride (64 + 8)
#define W2S 72    // w2T stride

#define SCALE_IN 256.0f            // 2^8
#define SCALE_W  2048.0f           // 2^11
#define INV_SC   (1.0f/524288.0f)  // 2^-19

// ---- LDS byte offsets ----
#define OFF_XH  0
#define OFF_XL  (OFF_XH + TROWS*XS*2)      // 33792
#define OFF_W1H (OFF_XL + TROWS*XS*2)      // 67584
#define OFF_W1L (OFF_W1H + 64*WS*2)        // 101376
#define OFF_H1H (OFF_W1L + 64*WS*2)        // 135168
#define OFF_H1L (OFF_H1H + TROWS*H1S*2)    // 144384
#define OFF_W2H (OFF_H1L + TROWS*H1S*2)    // 153600
#define OFF_W2L (OFF_W2H + 16*W2S*2)       // 155904
#define OFF_SUM (OFF_W2L + 16*W2S*2)       // 158208
#define SMEM_BYTES (OFF_SUM + 64*4)        // 158464 <= 163840 -> 1 block/CU

extern __shared__ char smem_raw[];

#define MFMA16(a,b,c) __builtin_amdgcn_mfma_f32_16x16x32_f16((a),(b),(c),0,0,0)

__device__ __forceinline__ void lds_barrier() {
    asm volatile("s_waitcnt lgkmcnt(0)\ns_barrier" ::: "memory");
}

__global__ __launch_bounds__(TPB, 2) void fused_mlp(
    const float* __restrict__ x,
    const float* __restrict__ wz1, const float* __restrict__ b1,
    const float* __restrict__ wz2, const float* __restrict__ b2,
    const float* __restrict__ wz3, const float* __restrict__ b3,
    float* __restrict__ Eout, float* __restrict__ block_sums,
    int ntiles)
{
    _Float16* xh  = (_Float16*)(smem_raw + OFF_XH);
    _Float16* xl  = (_Float16*)(smem_raw + OFF_XL);
    _Float16* w1h = (_Float16*)(smem_raw + OFF_W1H);
    _Float16* w1l = (_Float16*)(smem_raw + OFF_W1L);
    _Float16* h1h = (_Float16*)(smem_raw + OFF_H1H);
    _Float16* h1l = (_Float16*)(smem_raw + OFF_H1L);
    _Float16* w2h = (_Float16*)(smem_raw + OFF_W2H);
    _Float16* w2l = (_Float16*)(smem_raw + OFF_W2L);
    float* sums   = (float*)(smem_raw + OFF_SUM);

    const int tid  = threadIdx.x;
    const int lane = tid & 63;
    const int wid  = __builtin_amdgcn_readfirstlane(tid >> 6);
    const int l15  = lane & 15;
    const int g8   = (lane >> 4) * 8;

    const size_t blk_row0 = (size_t)blockIdx.x * ntiles * TROWS;

    // ---- prologue: issue x tile-0 loads first (HBM latency overlap) ----
    float4 xv[8];
    {
        const float4* xg = (const float4*)(x + blk_row0 * 256);
        #pragma unroll
        for (int c = 0; c < 8; ++c) xv[c] = xg[c * TPB + tid];
    }

    // ---- stage w1T as scaled f16 hi/lo (once) ----
    {
        const float4* wg = (const float4*)wz1;   // 4096 float4
        #pragma unroll
        for (int c = 0; c < 8; ++c) {
            const int q = c * TPB + tid;         // 0..4095
            const float4 v = wg[q];
            const int k = q >> 4, n0 = (q & 15) * 4;
            const float vv[4] = {v.x, v.y, v.z, v.w};
            #pragma unroll
            for (int i = 0; i < 4; ++i) {
                const float s = vv[i] * SCALE_W;
                const _Float16 h = (_Float16)s;
                w1h[(n0 + i) * WS + k] = h;
                w1l[(n0 + i) * WS + k] = (_Float16)(s - (float)h);
            }
        }
        if (tid < 256) {                         // w2T: 256 float4
            const float4 v = ((const float4*)wz2)[tid];
            const int k = tid >> 2, c0 = (tid & 3) * 4;
            const float vv[4] = {v.x, v.y, v.z, v.w};
            #pragma unroll
            for (int i = 0; i < 4; ++i) {
                const float s = vv[i] * SCALE_W;
                const _Float16 h = (_Float16)s;
                w2h[(c0 + i) * W2S + k] = h;
                w2l[(c0 + i) * W2S + k] = (_Float16)(s - (float)h);
            }
        }
    }

    // ---- per-lane constants ----
    const int rt  = wid >> 1;                 // rowtile 0..3 (layer 1)
    const int ntp = wid & 1;                  // col-pair 0..1
    const int col0 = (2 * ntp) * 16 + l15;
    const int col1 = (2 * ntp + 1) * 16 + l15;
    const float b1v0 = b1[col0], b1v1 = b1[col1];
    float b2v[4], w3v[4][4];
    #pragma unroll
    for (int i = 0; i < 4; ++i) {
        const int c2 = (lane >> 4) * 4 + i;
        b2v[i] = b2[c2];
        #pragma unroll
        for (int c3 = 0; c3 < 4; ++c3) w3v[i][c3] = wz3[c2 * 4 + c3];
    }
    const float b3v[4] = {b3[0], b3[1], b3[2], b3[3]};

    lds_barrier();   // weights staged

    // ---- persistent register fragments: w1 hi AND lo ----
    half8 Bh[8][2], Bl[8][2];
    #pragma unroll
    for (int kt = 0; kt < 8; ++kt) {
        Bh[kt][0] = *(const half8*)(w1h + col0 * WS + kt * 32 + g8);
        Bh[kt][1] = *(const half8*)(w1h + col1 * WS + kt * 32 + g8);
        Bl[kt][0] = *(const half8*)(w1l + col0 * WS + kt * 32 + g8);
        Bl[kt][1] = *(const half8*)(w1l + col1 * WS + kt * 32 + g8);
    }
    half8 A2h[2], A2l[2];                     // w2T A-frags (layer 2)
    #pragma unroll
    for (int kt = 0; kt < 2; ++kt) {
        A2h[kt] = *(const half8*)(w2h + l15 * W2S + kt * 32 + g8);
        A2l[kt] = *(const half8*)(w2l + l15 * W2S + kt * 32 + g8);
    }

    float local_sum = 0.f;

    for (int t = 0; t < ntiles; ++t) {
        // ---- convert regs -> LDS f16 hi/lo (row = c*8+wid, k = lane*4) ----
        #pragma unroll
        for (int c = 0; c < 8; ++c) {
            const float vv[4] = {xv[c].x, xv[c].y, xv[c].z, xv[c].w};
            half4 hh, hl;
            #pragma unroll
            for (int i = 0; i < 4; ++i) {
                const float s = vv[i] * SCALE_IN;
                const _Float16 h = (_Float16)s;
                hh[i] = h;
                hl[i] = (_Float16)(s - (float)h);
            }
            const int row = c * 8 + wid;
            *(half4*)(xh + row * XS + lane * 4) = hh;
            *(half4*)(xl + row * XS + lane * 4) = hl;
        }
        // ---- issue next-tile global loads (stay in flight across barrier) ----
        if (t + 1 < ntiles) {
            const float4* xg2 =
                (const float4*)(x + (blk_row0 + (size_t)(t + 1) * TROWS) * 256);
            #pragma unroll
            for (int c = 0; c < 8; ++c) xv[c] = xg2[c * TPB + tid];
        }
        lds_barrier();   // B1: x(t) visible

        // ---- layer 1: 3-term split MFMA; A from LDS, B from registers ----
        f32x4 acc0 = {0.f, 0.f, 0.f, 0.f}, acc1 = {0.f, 0.f, 0.f, 0.f};
        {
            const _Float16* xh_p = xh + (rt * 16 + l15) * XS;
            const _Float16* xl_p = xl + (rt * 16 + l15) * XS;
            #pragma unroll
            for (int kt = 0; kt < 8; ++kt) {
                const int ko = kt * 32 + g8;
                const half8 ah = *(const half8*)(xh_p + ko);
                const half8 al = *(const half8*)(xl_p + ko);
                acc0 = MFMA16(ah, Bh[kt][0], acc0);
                acc1 = MFMA16(ah, Bh[kt][1], acc1);
                acc0 = MFMA16(al, Bh[kt][0], acc0);
                acc1 = MFMA16(al, Bh[kt][1], acc1);
                acc0 = MFMA16(ah, Bl[kt][0], acc0);
                acc1 = MFMA16(ah, Bl[kt][1], acc1);
            }
        }
        // ---- epilogue: scale+bias+relu -> h1 f16 hi/lo ----
        #pragma unroll
        for (int i = 0; i < 4; ++i) {
            const int r = rt * 16 + (lane >> 4) * 4 + i;
            const float h0 = fmaxf(fmaf(acc0[i], INV_SC, b1v0), 0.f);
            const float h1f = fmaxf(fmaf(acc1[i], INV_SC, b1v1), 0.f);
            const float s0 = h0 * SCALE_IN;
            const _Float16 h0h = (_Float16)s0;
            h1h[r * H1S + col0] = h0h;
            h1l[r * H1S + col0] = (_Float16)(s0 - (float)h0h);
            const float s1 = h1f * SCALE_IN;
            const _Float16 h1hh = (_Float16)s1;
            h1h[r * H1S + col1] = h1hh;
            h1l[r * H1S + col1] = (_Float16)(s1 - (float)h1hh);
        }
        lds_barrier();   // B2: h1 ready

        // ---- layer 2 (MFMA) + layer 3 + exp: waves 0..3 ----
        if (wid < 4) {
            f32x4 a2 = {0.f, 0.f, 0.f, 0.f};
            const _Float16* hh_p = h1h + (wid * 16 + l15) * H1S;
            const _Float16* hl_p = h1l + (wid * 16 + l15) * H1S;
            #pragma unroll
            for (int kt = 0; kt < 2; ++kt) {
                const int ko = kt * 32 + g8;
                const half8 bh = *(const half8*)(hh_p + ko);
                const half8 bl = *(const half8*)(hl_p + ko);
                a2 = MFMA16(A2h[kt], bh, a2);
                a2 = MFMA16(A2l[kt], bh, a2);
                a2 = MFMA16(A2h[kt], bl, a2);
            }
            // lane holds h2pre for c2 = (lane>>4)*4+i, row = wid*16 + l15
            float p0 = 0.f, p1 = 0.f, p2 = 0.f, p3 = 0.f;
            #pragma unroll
            for (int i = 0; i < 4; ++i) {
                const float h2 = tanhf(fmaf(a2[i], INV_SC, b2v[i]));
                p0 = fmaf(h2, w3v[i][0], p0);
                p1 = fmaf(h2, w3v[i][1], p1);
                p2 = fmaf(h2, w3v[i][2], p2);
                p3 = fmaf(h2, w3v[i][3], p3);
            }
            p0 += __shfl_xor(p0, 16, 64); p0 += __shfl_xor(p0, 32, 64);
            p1 += __shfl_xor(p1, 16, 64); p1 += __shfl_xor(p1, 32, 64);
            p2 += __shfl_xor(p2, 16, 64); p2 += __shfl_xor(p2, 32, 64);
            p3 += __shfl_xor(p3, 16, 64); p3 += __shfl_xor(p3, 32, 64);
            if (lane < 16) {
                const float e0 = expf(p0 + b3v[0]);
                const float e1 = expf(p1 + b3v[1]);
                const float e2 = expf(p2 + b3v[2]);
                const float e3 = expf(p3 + b3v[3]);
                const size_t row = blk_row0 + (size_t)t * TROWS + wid * 16 + lane;
                float4 ev; ev.x = e0; ev.y = e1; ev.z = e2; ev.w = e3;
                *(float4*)(Eout + row * 4) = ev;
                local_sum += (e0 + e1) + (e2 + e3);
            }
        }
    }

    // ---- block exp-sum reduction (deterministic) ----
    #pragma unroll
    for (int off = 32; off > 0; off >>= 1)
        local_sum += __shfl_down(local_sum, off, 64);
    if (lane == 0) sums[wid] = local_sum;
    lds_barrier();
    if (tid == 0) {
        float s = 0.f;
        #pragma unroll
        for (int w = 0; w < 8; ++w) s += sums[w];
        block_sums[blockIdx.x] = s;
    }
}

// Merged reduce+scale: every block deterministically re-reduces the 256
// partials (1 KiB, L2-hot), then scales its own chunk of E.
__global__ __launch_bounds__(256) void scale_kernel(
    float* __restrict__ out, const float* __restrict__ block_sums)
{
    __shared__ float red[4];
    const int tid = threadIdx.x;
    float s = block_sums[tid];
    #pragma unroll
    for (int off = 32; off > 0; off >>= 1) s += __shfl_down(s, off, 64);
    if ((tid & 63) == 0) red[tid >> 6] = s;
    __syncthreads();
    const float inv = 1.0f / ((red[0] + red[1]) + (red[2] + red[3]));
    const int idx = blockIdx.x * 256 + tid;
    float4* o4 = (float4*)out;
    float4 v = o4[idx];
    v.x *= inv; v.y *= inv; v.z *= inv; v.w *= inv;
    o4[idx] = v;
}

extern "C" void kernel_launch(void* const* d_in, const int* in_sizes, int n_in,
                              void* d_out, int out_size, void* d_ws, size_t ws_size,
                              hipStream_t stream) {
    (void)n_in; (void)ws_size;
    const float* x   = (const float*)d_in[0];
    const float* wz1 = (const float*)d_in[1];
    const float* b1  = (const float*)d_in[2];
    const float* wz2 = (const float*)d_in[3];
    const float* b2  = (const float*)d_in[4];
    const float* wz3 = (const float*)d_in[5];
    const float* b3  = (const float*)d_in[6];
    float* out = (float*)d_out;

    float* block_sums = (float*)d_ws;            // GRID floats

    const int B = in_sizes[0] / 256;             // 262144
    const int ntiles = B / (GRID * TROWS);       // 16

    hipFuncSetAttribute((const void*)fused_mlp,
                        hipFuncAttributeMaxDynamicSharedMemorySize, SMEM_BYTES);

    fused_mlp<<<GRID, TPB, SMEM_BYTES, stream>>>(
        x, wz1, b1, wz2, b2, wz3, b3, out, block_sums, ntiles);

    const int n4 = out_size / 4;                 // 262144
    scale_kernel<<<n4 / 256, 256, 0, stream>>>(out, block_sums);
}